// Round 18
// baseline (380.547 us; speedup 1.0000x reference)
//
#include <hip/hip_runtime.h>
#include <hip/hip_fp16.h>

// GraphConv 3-layer GCN: N=100000 nodes, E=1280000 edges; dims 128->64->64->40.
constexpr int NN = 100000;
constexpr int NE = 1280000;
constexpr int NP = 100352;       // padded N (= 98 * 1024)

constexpr int NCHUNK = 64;         // edge chunks
constexpr int CHSZ = NE / NCHUNK;  // 20000 (exact)

// Segment geometry for hist2 and fill2: u16-packed LDS bins.
constexpr int HSEG = 32768;      // nodes per segment
constexpr int NHSEG = 4;         // 4*32768 = 131072 >= NN

typedef _Float16 half8_t __attribute__((ext_vector_type(8)));
typedef float floatx4 __attribute__((ext_vector_type(4)));

// ---------------------------------------------------------------------------
// Combined histogram: ONE pass over each edge chunk counts BOTH dst (pin)
// and src (pout) into u16-packed LDS bins (128 KB LDS). Per-(chunk,node)
// count <= 20000 < 65536 -> no carry across packed halves.
// ---------------------------------------------------------------------------
__global__ __launch_bounds__(1024) void hist2_kernel(
    const int* __restrict__ dst, const int* __restrict__ src,
    unsigned short* __restrict__ pin, unsigned short* __restrict__ pout) {
  __shared__ unsigned bin_in[HSEG / 2];   // 64 KB
  __shared__ unsigned bin_out[HSEG / 2];  // 64 KB
  const int s = blockIdx.x % NHSEG, c = blockIdx.x / NHSEG;
  const int t = threadIdx.x;
#pragma unroll 4
  for (int i = t; i < HSEG / 2; i += 1024) { bin_in[i] = 0; bin_out[i] = 0; }
  __syncthreads();
  const int lo = s * HSEG;
  const int beg = c * CHSZ;
  for (int e = beg + t; e < beg + CHSZ; e += 1024) {
    unsigned d = (unsigned)(dst[e] - lo);
    unsigned v = (unsigned)(src[e] - lo);
    if (d < (unsigned)HSEG) atomicAdd(&bin_in[d >> 1], 1u << ((d & 1) * 16));
    if (v < (unsigned)HSEG) atomicAdd(&bin_out[v >> 1], 1u << ((v & 1) * 16));
  }
  __syncthreads();
  // Dump as u32 words (nodes 2i, 2i+1); NN and c*NN even -> aligned.
  unsigned* pi = (unsigned*)(pin + (size_t)c * NN);
  unsigned* po = (unsigned*)(pout + (size_t)c * NN);
#pragma unroll 4
  for (int i = t; i < HSEG / 2; i += 1024) {
    int w = (lo >> 1) + i;
    if (2 * w < NN) { pi[w] = bin_in[i]; po[w] = bin_out[i]; }
  }
}

// ---------------------------------------------------------------------------
// Merge chunk-partials per node (cnt_in = sum, pin <- exclusive chunk prefix,
// norms) + FOLDED weight prep (first 15360 threads transpose W -> fp16 wt;
// wt region is disjoint from pout). Saves one launch.
// ---------------------------------------------------------------------------
__global__ __launch_bounds__(256) void merge_kernel(
    unsigned short* __restrict__ pin, const unsigned short* __restrict__ pout,
    int* __restrict__ cnt_in, float* __restrict__ norm_out,
    float* __restrict__ norm_in, const float* __restrict__ W0,
    const float* __restrict__ W1, const float* __restrict__ W2,
    __half* __restrict__ wt) {
  int n = blockIdx.x * 256 + threadIdx.x;
  // --- folded wprep: wt0[64][128] | wt1[64][64] | wt2[48][64] (pad 0) ---
  if (n < 15360) {
    if (n < 8192) {
      int c = n >> 7, k = n & 127;
      wt[n] = __float2half(W0[k * 64 + c]);
    } else if (n < 12288) {
      int q = n - 8192;
      int c = q >> 6, k = q & 63;
      wt[n] = __float2half(W1[k * 64 + c]);
    } else {
      int q = n - 12288;
      int c = q >> 6, k = q & 63;
      wt[n] = __float2half((c < 40) ? W2[k * 40 + c] : 0.0f);
    }
  }
  if (n >= NN) return;
  int run = 0;
#pragma unroll 8
  for (int c = 0; c < NCHUNK; ++c) {
    size_t idx = (size_t)c * NN + n;
    int v = pin[idx];
    pin[idx] = (unsigned short)run;
    run += v;
  }
  cnt_in[n] = run;
  int s = 0;
#pragma unroll 8
  for (int c = 0; c < NCHUNK; ++c) s += pout[(size_t)c * NN + n];
  norm_in[n]  = rsqrtf(fmaxf((float)run, 1.0f));
  norm_out[n] = rsqrtf(fmaxf((float)s, 1.0f));
}

// ---------------------------------------------------------------------------
// Single-block exclusive scan of cnt_in -> row_ptr (replaces the 3-kernel
// two-level scan: 2 fewer launches). 1024 threads x 98 elements; two passes
// over 400 KB + one 1024-wide Hillis-Steele in LDS.
// ---------------------------------------------------------------------------
__global__ __launch_bounds__(1024) void scan_kernel(
    const int* __restrict__ cnt, int* __restrict__ row_ptr) {
  constexpr int CH = NP / 1024;  // 98
  __shared__ int ts[1024];
  const int t = threadIdx.x;
  const int base = t * CH;
  int s = 0;
  for (int j = 0; j < CH; ++j) {
    int gi = base + j;
    s += (gi < NN) ? cnt[gi] : 0;
  }
  ts[t] = s;
  __syncthreads();
  for (int off = 1; off < 1024; off <<= 1) {
    int add = (t >= off) ? ts[t - off] : 0;
    __syncthreads();
    ts[t] += add;
    __syncthreads();
  }
  int run = ts[t] - s;  // exclusive prefix of this thread's chunk
  for (int j = 0; j < CH; ++j) {
    int gi = base + j;
    if (gi <= NN) row_ptr[gi] = run;
    if (gi < NN) run += cnt[gi];
  }
}

// ---------------------------------------------------------------------------
// CSR fill, rank-based: slot = row_ptr[d] + prefix[c][d] + local rank.
// Rank from packed-u16 LDS atomicAdd (old value) — a bijection onto
// [row_ptr[d], row_ptr[d]+deg) regardless of scheduling; no cross-lane ops.
// ---------------------------------------------------------------------------
__global__ __launch_bounds__(1024) void fill2_kernel(
    const int* __restrict__ src, const int* __restrict__ dst,
    const int* __restrict__ row_ptr, const unsigned short* __restrict__ pin,
    int* __restrict__ csr_src) {
  __shared__ unsigned rankb[HSEG / 2];  // 64 KB
  const int s = blockIdx.x % NHSEG, c = blockIdx.x / NHSEG;
  const int t = threadIdx.x;
#pragma unroll 4
  for (int i = t; i < HSEG / 2; i += 1024) rankb[i] = 0;
  __syncthreads();
  const int lo = s * HSEG;
  const int beg = c * CHSZ;
  const unsigned short* base = pin + (size_t)c * NN;
  for (int e = beg + t; e < beg + CHSZ; e += 1024) {
    int dn = dst[e];
    unsigned d = (unsigned)(dn - lo);
    if (d < (unsigned)HSEG) {
      unsigned sh = (d & 1) * 16;
      unsigned old = atomicAdd(&rankb[d >> 1], 1u << sh);  // LDS atomic
      int r = (int)((old >> sh) & 0xffffu);
      csr_src[row_ptr[dn] + (int)base[dn] + r] = src[e];
    }
  }
}

// ---------------------------------------------------------------------------
// MFMA GEMM:  m[row,:] = fp16( in[row,:] @ W )  (*norm_out if SCALE).
// Block = 64 rows, wave = 16 rows x COLS; zero LDS, zero barriers.
// A-frag direct from global rows; B-frag from fp16 W^T (L2-resident).
// C/D: col=lane&15, row=(lane>>4)*4+reg  [m89-verified mapping].
// ---------------------------------------------------------------------------
template <int K, int COLS, bool SCALE, typename TIN>
__global__ __launch_bounds__(256) void gemm_mfma_kernel(
    const TIN* __restrict__ in, const __half* __restrict__ wt,
    const float* __restrict__ norm_out, __half* __restrict__ out) {
  constexpr int NT = (COLS + 15) / 16;  // col tiles: 4 (C=64), 3 (C=40 padded)
  const int tid = threadIdx.x;
  const int w = tid >> 6;
  const int l = tid & 63;
  const int lr = l & 15;                // A-row / B-col within tile
  const int kg = l >> 4;                // k-group 0..3
  const int row0 = blockIdx.x * 64 + w * 16;
  const int arow = row0 + lr;

  floatx4 acc[NT];
#pragma unroll
  for (int ct = 0; ct < NT; ++ct) acc[ct] = (floatx4){0.f, 0.f, 0.f, 0.f};

#pragma unroll
  for (int kc = 0; kc < K; kc += 32) {
    half8_t a;
#pragma unroll
    for (int i = 0; i < 8; ++i) a[i] = (_Float16)0.0f;
    if (arow < NN) {
      if constexpr (sizeof(TIN) == 2) {
        a = *(const half8_t*)((const __half*)in + (size_t)arow * K + kc + kg * 8);
      } else {
        const float* p = (const float*)in + (size_t)arow * K + kc + kg * 8;
        float4 f0 = *(const float4*)p;
        float4 f1 = *(const float4*)(p + 4);
        a[0] = (_Float16)f0.x; a[1] = (_Float16)f0.y;
        a[2] = (_Float16)f0.z; a[3] = (_Float16)f0.w;
        a[4] = (_Float16)f1.x; a[5] = (_Float16)f1.y;
        a[6] = (_Float16)f1.z; a[7] = (_Float16)f1.w;
      }
    }
#pragma unroll
    for (int ct = 0; ct < NT; ++ct) {
      half8_t b = *(const half8_t*)((const __half*)wt +
                                    (size_t)(16 * ct + lr) * K + kc + kg * 8);
      acc[ct] = __builtin_amdgcn_mfma_f32_16x16x32_f16(a, b, acc[ct], 0, 0, 0);
    }
  }

#pragma unroll
  for (int ct = 0; ct < NT; ++ct) {
    int col = 16 * ct + lr;
    if (col < COLS) {
#pragma unroll
      for (int r = 0; r < 4; ++r) {
        int grow = row0 + kg * 4 + r;
        if (grow < NN) {
          float v = acc[ct][r];
          if constexpr (SCALE) v *= norm_out[grow];
          out[(size_t)grow * COLS + col] = __float2half(v);
        }
      }
    }
  }
}

// ---------------------------------------------------------------------------
// CSR gather from fp16 m — two nodes per wave (32 lanes each), hardened:
// every loop trip count is WAVE-uniform (degw = max of both halves' deg;
// kmax from degw); no early return. Every __shfl executes with all 64 lanes
// active (R10 rule at wave scope, by construction).
// Inner k-loop UNROLLED x4: four independent row-loads in flight per lane
// (the gather is outstanding-miss-latency bound — R9's C-independence).
// ---------------------------------------------------------------------------
template <int C, bool RELU>
__global__ __launch_bounds__(256) void gather_kernel(
    const __half* __restrict__ m, const int* __restrict__ row_ptr,
    const int* __restrict__ csr_src, const float* __restrict__ norm_in,
    const float* __restrict__ norm_out, const float* __restrict__ bias,
    void* __restrict__ outp) {
  constexpr int RV = C / 8;            // uint4 per row: 8 (C=64), 5 (C=40)
  constexpr unsigned RB = C * 2;       // row bytes: 128 or 80
  const int node = blockIdx.x * 8 + (threadIdx.x >> 5);
  const int l32 = threadIdx.x & 31;    // lane within half-wave
  const bool valid = node < NN;
  const int beg = valid ? row_ptr[node] : 0;
  const int deg = valid ? (row_ptr[node + 1] - beg) : 0;
  const int degw = max(deg, __shfl_xor(deg, 32));  // wave-uniform bound
  const int eg = l32 >> 3;             // edge group 0..3
  const int fl = l32 & 7;              // uint4 index within row
  const bool flok = (RV == 8) ? true : (fl < RV);
  const char* mb = (const char*)m;
  const unsigned fb = (unsigned)fl * 16u;

  float acc[8] = {};
  for (int base = 0; base < degw; base += 32) {    // uniform trip count
    const int nb = min(deg - base, 32);            // per-half, may be <= 0
    const int nbw = min(degw - base, 32);          // uniform
    const int idx = (l32 < nb) ? csr_src[beg + base + l32] : 0;
    const int kmax = (nbw + 3) >> 2;               // uniform trip count
    __half2 z = __float2half2_rn(0.f);
    __half2 h0 = z, h1 = z, h2 = z, h3 = z;        // <= 8 adds before flush
    for (int k = 0; k < kmax; k += 4) {
      int i0 = eg + 4 * k, i1 = i0 + 4, i2 = i0 + 8, i3 = i0 + 12;
      int s0 = __shfl(idx, (i0 < nb) ? i0 : 0, 32);  // all 64 lanes active
      int s1 = __shfl(idx, (i1 < nb) ? i1 : 0, 32);
      int s2 = __shfl(idx, (i2 < nb) ? i2 : 0, 32);
      int s3 = __shfl(idx, (i3 < nb) ? i3 : 0, 32);
      uint4 v0 = {0u, 0u, 0u, 0u}, v1 = {0u, 0u, 0u, 0u};
      uint4 v2 = {0u, 0u, 0u, 0u}, v3 = {0u, 0u, 0u, 0u};
      if (i0 < nb && flok) v0 = *(const uint4*)(mb + ((unsigned)s0 * RB + fb));
      if (i1 < nb && flok) v1 = *(const uint4*)(mb + ((unsigned)s1 * RB + fb));
      if (i2 < nb && flok) v2 = *(const uint4*)(mb + ((unsigned)s2 * RB + fb));
      if (i3 < nb && flok) v3 = *(const uint4*)(mb + ((unsigned)s3 * RB + fb));
      h0 = __hadd2(h0, __hadd2(__hadd2(*(const __half2*)&v0.x, *(const __half2*)&v1.x),
                               __hadd2(*(const __half2*)&v2.x, *(const __half2*)&v3.x)));
      h1 = __hadd2(h1, __hadd2(__hadd2(*(const __half2*)&v0.y, *(const __half2*)&v1.y),
                               __hadd2(*(const __half2*)&v2.y, *(const __half2*)&v3.y)));
      h2 = __hadd2(h2, __hadd2(__hadd2(*(const __half2*)&v0.z, *(const __half2*)&v1.z),
                               __hadd2(*(const __half2*)&v2.z, *(const __half2*)&v3.z)));
      h3 = __hadd2(h3, __hadd2(__hadd2(*(const __half2*)&v0.w, *(const __half2*)&v1.w),
                               __hadd2(*(const __half2*)&v2.w, *(const __half2*)&v3.w)));
    }
    float2 f0 = __half22float2(h0), f1 = __half22float2(h1);
    float2 f2 = __half22float2(h2), f3 = __half22float2(h3);
    acc[0] += f0.x; acc[1] += f0.y; acc[2] += f1.x; acc[3] += f1.y;
    acc[4] += f2.x; acc[5] += f2.y; acc[6] += f3.x; acc[7] += f3.y;
  }
  // 2-level reduction over the 4 edge groups (lane bits 3,4 — stays in half)
#pragma unroll
  for (int j = 0; j < 8; ++j) {
    acc[j] += __shfl_xor(acc[j], 8);
    acc[j] += __shfl_xor(acc[j], 16);
  }

  if (valid && eg == 0 && flok) {
    float ni = norm_in[node];
    float4 b0 = ((const float4*)bias)[2 * fl];
    float4 b1 = ((const float4*)bias)[2 * fl + 1];
    float r0[4], r1[4];
    r0[0] = fmaf(acc[0], ni, b0.x); r0[1] = fmaf(acc[1], ni, b0.y);
    r0[2] = fmaf(acc[2], ni, b0.z); r0[3] = fmaf(acc[3], ni, b0.w);
    r1[0] = fmaf(acc[4], ni, b1.x); r1[1] = fmaf(acc[5], ni, b1.y);
    r1[2] = fmaf(acc[6], ni, b1.z); r1[3] = fmaf(acc[7], ni, b1.w);
    if constexpr (RELU) {
      float no = norm_out[node];
#pragma unroll
      for (int j = 0; j < 4; ++j) {
        r0[j] = fmaxf(r0[j], 0.f) * no;
        r1[j] = fmaxf(r1[j], 0.f) * no;
      }
      __half2 p0 = __floats2half2_rn(r0[0], r0[1]);
      __half2 p1 = __floats2half2_rn(r0[2], r0[3]);
      __half2 p2 = __floats2half2_rn(r1[0], r1[1]);
      __half2 p3 = __floats2half2_rn(r1[2], r1[3]);
      uint4 st = {*(unsigned*)&p0, *(unsigned*)&p1,
                  *(unsigned*)&p2, *(unsigned*)&p3};
      ((uint4*)outp)[(size_t)node * RV + fl] = st;   // fp16 h
    } else {
      float* o = (float*)outp + (size_t)node * C + 8 * fl;
      float4 s0 = {r0[0], r0[1], r0[2], r0[3]};
      float4 s1 = {r1[0], r1[1], r1[2], r1[3]};
      *(float4*)o = s0;
      *(float4*)(o + 4) = s1;                        // fp32 final output
    }
  }
}

// ---------------------------------------------------------------------------
extern "C" void kernel_launch(void* const* d_in, const int* in_sizes, int n_in,
                              void* d_out, int out_size, void* d_ws, size_t ws_size,
                              hipStream_t stream) {
  const float* x    = (const float*)d_in[0];
  const float* W0   = (const float*)d_in[1];
  const float* b0   = (const float*)d_in[2];
  const float* W1   = (const float*)d_in[3];
  const float* b1   = (const float*)d_in[4];
  const float* W2   = (const float*)d_in[5];
  const float* b2   = (const float*)d_in[6];
  const int*   esrc = (const int*)d_in[7];
  const int*   edst = (const int*)d_in[8];
  float* out = (float*)d_out;

  // Workspace (4B units): norms/row_ptr/cnt_in + csr_src[NE] +
  // m-region[NN*64 floats] + h-region[NN*64 floats].
  // m, h fp16 occupy the FRONT half (12.8 MB) of their regions.
  // Aliases (stream-ordered, no overlap in time or space):
  //   pin  = u16 NCHUNK*NN (12.8 MB) in m-region front (dead before gemm0)
  //   pout = u16 NCHUNK*NN in h-region front (dead after merge)
  //   wt   = fp16 15360 in h-region BACK half (merge writes, gemms read)
  float*  f        = (float*)d_ws;
  float*  norm_out = f;
  float*  norm_in  = f + NP;
  int*    row_ptr  = (int*)(f + 2 * NP);
  int*    cnt_in   = row_ptr + NP;
  int*    csr_src  = cnt_in + NP;
  float*  mreg     = (float*)(csr_src + NE);
  float*  hreg     = mreg + NN * 64;
  __half* m        = (__half*)mreg;
  __half* h        = (__half*)hreg;
  unsigned short* pin  = (unsigned short*)mreg;
  unsigned short* pout = (unsigned short*)hreg;
  __half* wt       = (__half*)hreg + (size_t)NN * 64;  // back half of h-region

  // --- CSR build (dst-sorted) + norms + wprep: zero global atomics ---
  hist2_kernel<<<NHSEG * NCHUNK, 1024, 0, stream>>>(edst, esrc, pin, pout);
  merge_kernel<<<(NN + 255) / 256, 256, 0, stream>>>(
      pin, pout, cnt_in, norm_out, norm_in, W0, W1, W2, wt);
  scan_kernel<<<1, 1024, 0, stream>>>(cnt_in, row_ptr);
  fill2_kernel<<<NHSEG * NCHUNK, 1024, 0, stream>>>(esrc, edst, row_ptr, pin, csr_src);

  const int gb = (NN + 63) / 64;
  const int gg = (NN + 7) / 8;   // 8 nodes per 256-thread block (2 per wave)

  // Layer 0: m = fp16((x @ W0) * norm_out) ; h = fp16(relu(agg*ni + b0)*no)
  gemm_mfma_kernel<128, 64, true, float><<<gb, 256, 0, stream>>>(x, wt, norm_out, m);
  gather_kernel<64, true><<<gg, 256, 0, stream>>>(m, row_ptr, csr_src, norm_in, norm_out, b0, h);

  // Layer 1: m = fp16(h @ W1) ; h = fp16(relu(agg*ni + b1)*no)
  gemm_mfma_kernel<64, 64, false, __half><<<gb, 256, 0, stream>>>(h, wt + 8192, nullptr, m);
  gather_kernel<64, true><<<gg, 256, 0, stream>>>(m, row_ptr, csr_src, norm_in, norm_out, b1, h);

  // Layer 2: m = fp16(h @ W2) (40 cols) ; out = agg*ni + b2 (fp32)
  gemm_mfma_kernel<64, 40, false, __half><<<gb, 256, 0, stream>>>(h, wt + 12288, nullptr, m);
  gather_kernel<40, false><<<gg, 256, 0, stream>>>(m, row_ptr, csr_src, norm_in, norm_out, b2, out);
}

// Round 19
// 195.843 us; speedup vs baseline: 1.9431x; 1.9431x over previous
//
#include <hip/hip_runtime.h>
#include <hip/hip_fp16.h>

// GraphConv 3-layer GCN: N=100000 nodes, E=1280000 edges; dims 128->64->64->40.
constexpr int NN = 100000;
constexpr int NE = 1280000;
constexpr int NP = 100352;       // padded N (= 98 * 1024)
constexpr int NBLK = NP / 1024;  // 98 scan chunks

constexpr int NCHUNK = 64;         // edge chunks
constexpr int CHSZ = NE / NCHUNK;  // 20000 (exact)

// Segment geometry for hist2 and fill2: u16-packed LDS bins.
constexpr int HSEG = 32768;      // nodes per segment
constexpr int NHSEG = 4;         // 4*32768 = 131072 >= NN

typedef _Float16 half8_t __attribute__((ext_vector_type(8)));
typedef float floatx4 __attribute__((ext_vector_type(4)));

// ---------------------------------------------------------------------------
// Combined histogram: ONE pass over each edge chunk counts BOTH dst (pin)
// and src (pout) into u16-packed LDS bins (128 KB LDS). Per-(chunk,node)
// count <= 20000 < 65536 -> no carry across packed halves.
// ---------------------------------------------------------------------------
__global__ __launch_bounds__(1024) void hist2_kernel(
    const int* __restrict__ dst, const int* __restrict__ src,
    unsigned short* __restrict__ pin, unsigned short* __restrict__ pout) {
  __shared__ unsigned bin_in[HSEG / 2];   // 64 KB
  __shared__ unsigned bin_out[HSEG / 2];  // 64 KB
  const int s = blockIdx.x % NHSEG, c = blockIdx.x / NHSEG;
  const int t = threadIdx.x;
#pragma unroll 4
  for (int i = t; i < HSEG / 2; i += 1024) { bin_in[i] = 0; bin_out[i] = 0; }
  __syncthreads();
  const int lo = s * HSEG;
  const int beg = c * CHSZ;
  for (int e = beg + t; e < beg + CHSZ; e += 1024) {
    unsigned d = (unsigned)(dst[e] - lo);
    unsigned v = (unsigned)(src[e] - lo);
    if (d < (unsigned)HSEG) atomicAdd(&bin_in[d >> 1], 1u << ((d & 1) * 16));
    if (v < (unsigned)HSEG) atomicAdd(&bin_out[v >> 1], 1u << ((v & 1) * 16));
  }
  __syncthreads();
  // Dump as u32 words (nodes 2i, 2i+1); NN and c*NN even -> aligned.
  unsigned* pi = (unsigned*)(pin + (size_t)c * NN);
  unsigned* po = (unsigned*)(pout + (size_t)c * NN);
#pragma unroll 4
  for (int i = t; i < HSEG / 2; i += 1024) {
    int w = (lo >> 1) + i;
    if (2 * w < NN) { pi[w] = bin_in[i]; po[w] = bin_out[i]; }
  }
}

// ---------------------------------------------------------------------------
// Merge chunk-partials per node (cnt_in = sum, pin <- exclusive chunk prefix,
// norms) + FOLDED weight prep (first 15360 threads transpose W -> fp16 wt;
// wt region is disjoint from pout). Saves one launch.
// ---------------------------------------------------------------------------
__global__ __launch_bounds__(256) void merge_kernel(
    unsigned short* __restrict__ pin, const unsigned short* __restrict__ pout,
    int* __restrict__ cnt_in, float* __restrict__ norm_out,
    float* __restrict__ norm_in, const float* __restrict__ W0,
    const float* __restrict__ W1, const float* __restrict__ W2,
    __half* __restrict__ wt) {
  int n = blockIdx.x * 256 + threadIdx.x;
  // --- folded wprep: wt0[64][128] | wt1[64][64] | wt2[48][64] (pad 0) ---
  if (n < 15360) {
    if (n < 8192) {
      int c = n >> 7, k = n & 127;
      wt[n] = __float2half(W0[k * 64 + c]);
    } else if (n < 12288) {
      int q = n - 8192;
      int c = q >> 6, k = q & 63;
      wt[n] = __float2half(W1[k * 64 + c]);
    } else {
      int q = n - 12288;
      int c = q >> 6, k = q & 63;
      wt[n] = __float2half((c < 40) ? W2[k * 40 + c] : 0.0f);
    }
  }
  if (n >= NN) return;
  int run = 0;
#pragma unroll 8
  for (int c = 0; c < NCHUNK; ++c) {
    size_t idx = (size_t)c * NN + n;
    int v = pin[idx];
    pin[idx] = (unsigned short)run;
    run += v;
  }
  cnt_in[n] = run;
  int s = 0;
#pragma unroll 8
  for (int c = 0; c < NCHUNK; ++c) s += pout[(size_t)c * NN + n];
  norm_in[n]  = rsqrtf(fmaxf((float)run, 1.0f));
  norm_out[n] = rsqrtf(fmaxf((float)s, 1.0f));
}

// ---------------------------------------------------------------------------
// Two-level exclusive scan of cnt_in -> row_ptr (98 + 1 + 98 blocks).
// R18 lesson: a single-block scan serialized 98 dependent L2 loads per
// thread on ONE CU (197 us). Launch overhead (~5 us for 2 extra kernels)
// is far cheaper than device-wide serialization.
// ---------------------------------------------------------------------------
__global__ __launch_bounds__(256) void chunk_sum_kernel(
    const int* __restrict__ cnt, int* __restrict__ partial) {
  int t = threadIdx.x;
  int base = blockIdx.x * 1024 + t * 4;
  int s = 0;
#pragma unroll
  for (int j = 0; j < 4; ++j) {
    int gi = base + j;
    s += (gi < NN) ? cnt[gi] : 0;
  }
  __shared__ int r[256];
  r[t] = s;
  __syncthreads();
  for (int off = 128; off > 0; off >>= 1) {
    if (t < off) r[t] += r[t + off];
    __syncthreads();
  }
  if (t == 0) partial[blockIdx.x] = r[0];
}

__global__ __launch_bounds__(128) void partial_scan_kernel(int* __restrict__ partial) {
  int t = threadIdx.x;
  int v = (t < NBLK) ? partial[t] : 0;
  __shared__ int s[128];
  s[t] = v;
  __syncthreads();
  for (int off = 1; off < 128; off <<= 1) {
    int add = (t >= off) ? s[t - off] : 0;
    __syncthreads();
    s[t] += add;
    __syncthreads();
  }
  if (t < NBLK) partial[t] = s[t] - v;  // exclusive
}

__global__ __launch_bounds__(256) void chunk_scan_kernel(
    const int* __restrict__ cnt, const int* __restrict__ partial,
    int* __restrict__ row_ptr) {
  int t = threadIdx.x;
  int base = blockIdx.x * 1024 + t * 4;
  int c[4];
#pragma unroll
  for (int j = 0; j < 4; ++j) {
    int gi = base + j;
    c[j] = (gi < NN) ? cnt[gi] : 0;
  }
  int tsum = c[0] + c[1] + c[2] + c[3];
  __shared__ int s[256];
  s[t] = tsum;
  __syncthreads();
  for (int off = 1; off < 256; off <<= 1) {
    int add = (t >= off) ? s[t - off] : 0;
    __syncthreads();
    s[t] += add;
    __syncthreads();
  }
  int run = s[t] - tsum + partial[blockIdx.x];
#pragma unroll
  for (int j = 0; j < 4; ++j) {
    int gi = base + j;
    if (gi <= NN) row_ptr[gi] = run;
    run += c[j];
  }
}

// ---------------------------------------------------------------------------
// CSR fill, rank-based: slot = row_ptr[d] + prefix[c][d] + local rank.
// Rank from packed-u16 LDS atomicAdd (old value) — a bijection onto
// [row_ptr[d], row_ptr[d]+deg) regardless of scheduling; no cross-lane ops.
// ---------------------------------------------------------------------------
__global__ __launch_bounds__(1024) void fill2_kernel(
    const int* __restrict__ src, const int* __restrict__ dst,
    const int* __restrict__ row_ptr, const unsigned short* __restrict__ pin,
    int* __restrict__ csr_src) {
  __shared__ unsigned rankb[HSEG / 2];  // 64 KB
  const int s = blockIdx.x % NHSEG, c = blockIdx.x / NHSEG;
  const int t = threadIdx.x;
#pragma unroll 4
  for (int i = t; i < HSEG / 2; i += 1024) rankb[i] = 0;
  __syncthreads();
  const int lo = s * HSEG;
  const int beg = c * CHSZ;
  const unsigned short* base = pin + (size_t)c * NN;
  for (int e = beg + t; e < beg + CHSZ; e += 1024) {
    int dn = dst[e];
    unsigned d = (unsigned)(dn - lo);
    if (d < (unsigned)HSEG) {
      unsigned sh = (d & 1) * 16;
      unsigned old = atomicAdd(&rankb[d >> 1], 1u << sh);  // LDS atomic
      int r = (int)((old >> sh) & 0xffffu);
      csr_src[row_ptr[dn] + (int)base[dn] + r] = src[e];
    }
  }
}

// ---------------------------------------------------------------------------
// MFMA GEMM:  m[row,:] = fp16( in[row,:] @ W )  (*norm_out if SCALE).
// Block = 64 rows, wave = 16 rows x COLS; zero LDS, zero barriers.
// A-frag direct from global rows; B-frag from fp16 W^T (L2-resident).
// C/D: col=lane&15, row=(lane>>4)*4+reg  [m89-verified mapping].
// ---------------------------------------------------------------------------
template <int K, int COLS, bool SCALE, typename TIN>
__global__ __launch_bounds__(256) void gemm_mfma_kernel(
    const TIN* __restrict__ in, const __half* __restrict__ wt,
    const float* __restrict__ norm_out, __half* __restrict__ out) {
  constexpr int NT = (COLS + 15) / 16;  // col tiles: 4 (C=64), 3 (C=40 padded)
  const int tid = threadIdx.x;
  const int w = tid >> 6;
  const int l = tid & 63;
  const int lr = l & 15;                // A-row / B-col within tile
  const int kg = l >> 4;                // k-group 0..3
  const int row0 = blockIdx.x * 64 + w * 16;
  const int arow = row0 + lr;

  floatx4 acc[NT];
#pragma unroll
  for (int ct = 0; ct < NT; ++ct) acc[ct] = (floatx4){0.f, 0.f, 0.f, 0.f};

#pragma unroll
  for (int kc = 0; kc < K; kc += 32) {
    half8_t a;
#pragma unroll
    for (int i = 0; i < 8; ++i) a[i] = (_Float16)0.0f;
    if (arow < NN) {
      if constexpr (sizeof(TIN) == 2) {
        a = *(const half8_t*)((const __half*)in + (size_t)arow * K + kc + kg * 8);
      } else {
        const float* p = (const float*)in + (size_t)arow * K + kc + kg * 8;
        float4 f0 = *(const float4*)p;
        float4 f1 = *(const float4*)(p + 4);
        a[0] = (_Float16)f0.x; a[1] = (_Float16)f0.y;
        a[2] = (_Float16)f0.z; a[3] = (_Float16)f0.w;
        a[4] = (_Float16)f1.x; a[5] = (_Float16)f1.y;
        a[6] = (_Float16)f1.z; a[7] = (_Float16)f1.w;
      }
    }
#pragma unroll
    for (int ct = 0; ct < NT; ++ct) {
      half8_t b = *(const half8_t*)((const __half*)wt +
                                    (size_t)(16 * ct + lr) * K + kc + kg * 8);
      acc[ct] = __builtin_amdgcn_mfma_f32_16x16x32_f16(a, b, acc[ct], 0, 0, 0);
    }
  }

#pragma unroll
  for (int ct = 0; ct < NT; ++ct) {
    int col = 16 * ct + lr;
    if (col < COLS) {
#pragma unroll
      for (int r = 0; r < 4; ++r) {
        int grow = row0 + kg * 4 + r;
        if (grow < NN) {
          float v = acc[ct][r];
          if constexpr (SCALE) v *= norm_out[grow];
          out[(size_t)grow * COLS + col] = __float2half(v);
        }
      }
    }
  }
}

// ---------------------------------------------------------------------------
// CSR gather from fp16 m — two nodes per wave (32 lanes each), hardened:
// every loop trip count is WAVE-uniform (degw = max of both halves' deg;
// kmax from degw); no early return. Every __shfl executes with all 64 lanes
// active (R10 rule at wave scope, by construction).
// Inner k-loop UNROLLED x4: four independent row-loads in flight per lane
// (the gather is outstanding-miss-latency bound — R9's C-independence).
// ---------------------------------------------------------------------------
template <int C, bool RELU>
__global__ __launch_bounds__(256) void gather_kernel(
    const __half* __restrict__ m, const int* __restrict__ row_ptr,
    const int* __restrict__ csr_src, const float* __restrict__ norm_in,
    const float* __restrict__ norm_out, const float* __restrict__ bias,
    void* __restrict__ outp) {
  constexpr int RV = C / 8;            // uint4 per row: 8 (C=64), 5 (C=40)
  constexpr unsigned RB = C * 2;       // row bytes: 128 or 80
  const int node = blockIdx.x * 8 + (threadIdx.x >> 5);
  const int l32 = threadIdx.x & 31;    // lane within half-wave
  const bool valid = node < NN;
  const int beg = valid ? row_ptr[node] : 0;
  const int deg = valid ? (row_ptr[node + 1] - beg) : 0;
  const int degw = max(deg, __shfl_xor(deg, 32));  // wave-uniform bound
  const int eg = l32 >> 3;             // edge group 0..3
  const int fl = l32 & 7;              // uint4 index within row
  const bool flok = (RV == 8) ? true : (fl < RV);
  const char* mb = (const char*)m;
  const unsigned fb = (unsigned)fl * 16u;

  float acc[8] = {};
  for (int base = 0; base < degw; base += 32) {    // uniform trip count
    const int nb = min(deg - base, 32);            // per-half, may be <= 0
    const int nbw = min(degw - base, 32);          // uniform
    const int idx = (l32 < nb) ? csr_src[beg + base + l32] : 0;
    const int kmax = (nbw + 3) >> 2;               // uniform trip count
    __half2 z = __float2half2_rn(0.f);
    __half2 h0 = z, h1 = z, h2 = z, h3 = z;        // <= 8 adds before flush
    for (int k = 0; k < kmax; k += 4) {
      int i0 = eg + 4 * k, i1 = i0 + 4, i2 = i0 + 8, i3 = i0 + 12;
      int s0 = __shfl(idx, (i0 < nb) ? i0 : 0, 32);  // all 64 lanes active
      int s1 = __shfl(idx, (i1 < nb) ? i1 : 0, 32);
      int s2 = __shfl(idx, (i2 < nb) ? i2 : 0, 32);
      int s3 = __shfl(idx, (i3 < nb) ? i3 : 0, 32);
      uint4 v0 = {0u, 0u, 0u, 0u}, v1 = {0u, 0u, 0u, 0u};
      uint4 v2 = {0u, 0u, 0u, 0u}, v3 = {0u, 0u, 0u, 0u};
      if (i0 < nb && flok) v0 = *(const uint4*)(mb + ((unsigned)s0 * RB + fb));
      if (i1 < nb && flok) v1 = *(const uint4*)(mb + ((unsigned)s1 * RB + fb));
      if (i2 < nb && flok) v2 = *(const uint4*)(mb + ((unsigned)s2 * RB + fb));
      if (i3 < nb && flok) v3 = *(const uint4*)(mb + ((unsigned)s3 * RB + fb));
      h0 = __hadd2(h0, __hadd2(__hadd2(*(const __half2*)&v0.x, *(const __half2*)&v1.x),
                               __hadd2(*(const __half2*)&v2.x, *(const __half2*)&v3.x)));
      h1 = __hadd2(h1, __hadd2(__hadd2(*(const __half2*)&v0.y, *(const __half2*)&v1.y),
                               __hadd2(*(const __half2*)&v2.y, *(const __half2*)&v3.y)));
      h2 = __hadd2(h2, __hadd2(__hadd2(*(const __half2*)&v0.z, *(const __half2*)&v1.z),
                               __hadd2(*(const __half2*)&v2.z, *(const __half2*)&v3.z)));
      h3 = __hadd2(h3, __hadd2(__hadd2(*(const __half2*)&v0.w, *(const __half2*)&v1.w),
                               __hadd2(*(const __half2*)&v2.w, *(const __half2*)&v3.w)));
    }
    float2 f0 = __half22float2(h0), f1 = __half22float2(h1);
    float2 f2 = __half22float2(h2), f3 = __half22float2(h3);
    acc[0] += f0.x; acc[1] += f0.y; acc[2] += f1.x; acc[3] += f1.y;
    acc[4] += f2.x; acc[5] += f2.y; acc[6] += f3.x; acc[7] += f3.y;
  }
  // 2-level reduction over the 4 edge groups (lane bits 3,4 — stays in half)
#pragma unroll
  for (int j = 0; j < 8; ++j) {
    acc[j] += __shfl_xor(acc[j], 8);
    acc[j] += __shfl_xor(acc[j], 16);
  }

  if (valid && eg == 0 && flok) {
    float ni = norm_in[node];
    float4 b0 = ((const float4*)bias)[2 * fl];
    float4 b1 = ((const float4*)bias)[2 * fl + 1];
    float r0[4], r1[4];
    r0[0] = fmaf(acc[0], ni, b0.x); r0[1] = fmaf(acc[1], ni, b0.y);
    r0[2] = fmaf(acc[2], ni, b0.z); r0[3] = fmaf(acc[3], ni, b0.w);
    r1[0] = fmaf(acc[4], ni, b1.x); r1[1] = fmaf(acc[5], ni, b1.y);
    r1[2] = fmaf(acc[6], ni, b1.z); r1[3] = fmaf(acc[7], ni, b1.w);
    if constexpr (RELU) {
      float no = norm_out[node];
#pragma unroll
      for (int j = 0; j < 4; ++j) {
        r0[j] = fmaxf(r0[j], 0.f) * no;
        r1[j] = fmaxf(r1[j], 0.f) * no;
      }
      __half2 p0 = __floats2half2_rn(r0[0], r0[1]);
      __half2 p1 = __floats2half2_rn(r0[2], r0[3]);
      __half2 p2 = __floats2half2_rn(r1[0], r1[1]);
      __half2 p3 = __floats2half2_rn(r1[2], r1[3]);
      uint4 st = {*(unsigned*)&p0, *(unsigned*)&p1,
                  *(unsigned*)&p2, *(unsigned*)&p3};
      ((uint4*)outp)[(size_t)node * RV + fl] = st;   // fp16 h
    } else {
      float* o = (float*)outp + (size_t)node * C + 8 * fl;
      float4 s0 = {r0[0], r0[1], r0[2], r0[3]};
      float4 s1 = {r1[0], r1[1], r1[2], r1[3]};
      *(float4*)o = s0;
      *(float4*)(o + 4) = s1;                        // fp32 final output
    }
  }
}

// ---------------------------------------------------------------------------
extern "C" void kernel_launch(void* const* d_in, const int* in_sizes, int n_in,
                              void* d_out, int out_size, void* d_ws, size_t ws_size,
                              hipStream_t stream) {
  const float* x    = (const float*)d_in[0];
  const float* W0   = (const float*)d_in[1];
  const float* b0   = (const float*)d_in[2];
  const float* W1   = (const float*)d_in[3];
  const float* b1   = (const float*)d_in[4];
  const float* W2   = (const float*)d_in[5];
  const float* b2   = (const float*)d_in[6];
  const int*   esrc = (const int*)d_in[7];
  const int*   edst = (const int*)d_in[8];
  float* out = (float*)d_out;

  // Workspace (4B units): norms/row_ptr/cnt_in/partial + csr_src[NE] +
  // m-region[NN*64 floats] + h-region[NN*64 floats].
  // m, h fp16 occupy the FRONT half (12.8 MB) of their regions.
  // Aliases (stream-ordered, no overlap in time or space):
  //   pin  = u16 NCHUNK*NN (12.8 MB) in m-region front (dead before gemm0)
  //   pout = u16 NCHUNK*NN in h-region front (dead after merge)
  //   wt   = fp16 15360 in h-region BACK half (merge writes, gemms read)
  float*  f        = (float*)d_ws;
  float*  norm_out = f;
  float*  norm_in  = f + NP;
  int*    row_ptr  = (int*)(f + 2 * NP);
  int*    cnt_in   = row_ptr + NP;
  int*    partial  = cnt_in + NP;
  int*    csr_src  = partial + 128;
  float*  mreg     = (float*)(csr_src + NE);
  float*  hreg     = mreg + NN * 64;
  __half* m        = (__half*)mreg;
  __half* h        = (__half*)hreg;
  unsigned short* pin  = (unsigned short*)mreg;
  unsigned short* pout = (unsigned short*)hreg;
  __half* wt       = (__half*)hreg + (size_t)NN * 64;  // back half of h-region

  // --- CSR build (dst-sorted) + norms + wprep: zero global atomics ---
  hist2_kernel<<<NHSEG * NCHUNK, 1024, 0, stream>>>(edst, esrc, pin, pout);
  merge_kernel<<<(NN + 255) / 256, 256, 0, stream>>>(
      pin, pout, cnt_in, norm_out, norm_in, W0, W1, W2, wt);
  chunk_sum_kernel<<<NBLK, 256, 0, stream>>>(cnt_in, partial);
  partial_scan_kernel<<<1, 128, 0, stream>>>(partial);
  chunk_scan_kernel<<<NBLK, 256, 0, stream>>>(cnt_in, partial, row_ptr);
  fill2_kernel<<<NHSEG * NCHUNK, 1024, 0, stream>>>(esrc, edst, row_ptr, pin, csr_src);

  const int gb = (NN + 63) / 64;
  const int gg = (NN + 7) / 8;   // 8 nodes per 256-thread block (2 per wave)

  // Layer 0: m = fp16((x @ W0) * norm_out) ; h = fp16(relu(agg*ni + b0)*no)
  gemm_mfma_kernel<128, 64, true, float><<<gb, 256, 0, stream>>>(x, wt, norm_out, m);
  gather_kernel<64, true><<<gg, 256, 0, stream>>>(m, row_ptr, csr_src, norm_in, norm_out, b0, h);

  // Layer 1: m = fp16(h @ W1) ; h = fp16(relu(agg*ni + b1)*no)
  gemm_mfma_kernel<64, 64, false, __half><<<gb, 256, 0, stream>>>(h, wt + 8192, nullptr, m);
  gather_kernel<64, true><<<gg, 256, 0, stream>>>(m, row_ptr, csr_src, norm_in, norm_out, b1, h);

  // Layer 2: m = fp16(h @ W2) (40 cols) ; out = agg*ni + b2 (fp32)
  gemm_mfma_kernel<64, 40, false, __half><<<gb, 256, 0, stream>>>(h, wt + 12288, nullptr, m);
  gather_kernel<40, false><<<gg, 256, 0, stream>>>(m, row_ptr, csr_src, norm_in, norm_out, b2, out);
}